// Round 18
// baseline (178.641 us; speedup 1.0000x reference)
//
#include <hip/hip_runtime.h>
#include <hip/hip_bf16.h>

typedef __bf16 bf16;
typedef __bf16 bf16x8 __attribute__((ext_vector_type(8)));
typedef __bf16 bf16x4 __attribute__((ext_vector_type(4)));
typedef float f32x4 __attribute__((ext_vector_type(4)));

#define MFMA16(a, b, c) __builtin_amdgcn_mfma_f32_16x16x32_bf16((a), (b), (c), 0, 0, 0)

constexpr int S = 4096;
constexpr int E = 1024;
constexpr int H = 16;
constexpr int HD = 64;
constexpr float NEG = -1e30f;
// scores in log2 domain: fold 1/sqrt(64) * log2(e) into Q
constexpr float QSCALE = 0.125f * 1.44269504088896f;

__device__ inline bf16x8 load_f32x8_as_bf16(const float* __restrict__ p) {
  float4 u0 = *reinterpret_cast<const float4*>(p);
  float4 u1 = *reinterpret_cast<const float4*>(p + 4);
  bf16x8 r;
  r[0] = (bf16)u0.x; r[1] = (bf16)u0.y; r[2] = (bf16)u0.z; r[3] = (bf16)u0.w;
  r[4] = (bf16)u1.x; r[5] = (bf16)u1.y; r[6] = (bf16)u1.z; r[7] = (bf16)u1.w;
  return r;
}

// ---------------- QKV projection (+ wo->bf16 folded in as blockIdx.y == 16) ----------------
// Q pre-scaled by QSCALE; V written TRANSPOSED: vt[h][d][s]
__global__ __launch_bounds__(256) void qkv_cvt_kernel(
    const float* __restrict__ x, const float* __restrict__ wq,
    const float* __restrict__ wk, const float* __restrict__ wv,
    const float* __restrict__ wo,
    bf16* __restrict__ qb, bf16* __restrict__ kb, bf16* __restrict__ vt,
    bf16* __restrict__ wob) {
  if (blockIdx.y == 16) {  // wo -> bf16 conversion lane
    for (int i = (blockIdx.x * 256 + threadIdx.x) * 4; i < E * E; i += 64 * 256 * 4) {
      float4 f = *reinterpret_cast<const float4*>(wo + i);
      bf16x4 b;
      b[0] = (bf16)f.x; b[1] = (bf16)f.y; b[2] = (bf16)f.z; b[3] = (bf16)f.w;
      *reinterpret_cast<bf16x4*>(wob + i) = b;
    }
    return;
  }
  const int h = blockIdx.y;
  const int s0 = blockIdx.x * 64;
  const int w = threadIdx.x >> 6;
  const int l = threadIdx.x & 63;
  const int lg = l >> 4, lr = l & 15;

  bf16x8 af[2];
  {
    const float* xp = x + (size_t)(s0 + w * 16 + lr) * E + h * HD;
    af[0] = load_f32x8_as_bf16(xp + lg * 8);
    af[1] = load_f32x8_as_bf16(xp + 32 + lg * 8);
  }
  const float* Wsrc[3] = {wq + (size_t)h * HD * HD, wk + (size_t)h * HD * HD,
                          wv + (size_t)h * HD * HD};
#pragma unroll
  for (int pj = 0; pj < 3; ++pj) {
    f32x4 acc[4];
#pragma unroll
    for (int ot = 0; ot < 4; ++ot) acc[ot] = f32x4{0.f, 0.f, 0.f, 0.f};
#pragma unroll
    for (int ks = 0; ks < 2; ++ks) {
#pragma unroll
      for (int ot = 0; ot < 4; ++ot) {
        bf16x8 bfr = load_f32x8_as_bf16(Wsrc[pj] + (size_t)(ot * 16 + lr) * HD + ks * 32 + lg * 8);
        acc[ot] = MFMA16(af[ks], bfr, acc[ot]);
      }
    }
    if (pj == 2) {
      // V^T store: vt[(h*HD + o)][s]
#pragma unroll
      for (int ot = 0; ot < 4; ++ot) {
        bf16x4 b;
#pragma unroll
        for (int r = 0; r < 4; ++r) b[r] = (bf16)acc[ot][r];
        *reinterpret_cast<bf16x4*>(vt + (size_t)(h * HD + ot * 16 + lr) * S +
                                   s0 + w * 16 + lg * 4) = b;
      }
    } else {
      const float scale = (pj == 0) ? QSCALE : 1.0f;
      bf16* op = ((pj == 0) ? qb : kb) + (size_t)h * S * HD;
#pragma unroll
      for (int ot = 0; ot < 4; ++ot)
#pragma unroll
        for (int r = 0; r < 4; ++r)
          op[(size_t)(s0 + w * 16 + lg * 4 + r) * HD + ot * 16 + lr] =
              (bf16)(acc[ot][r] * scale);
    }
  }
}

// ---------------- causal flash attention: MFMA16, split-kv for heavy tiles ----------------
// R17-verified stage body. q-tiles qt>=32 are processed by TWO blocks over
// disjoint kv ranges ([0,hi) and [hi,qt], hi=(qt+2)/2) -> every block runs
// <=33 stages (critical path halved). A-half writes ob normalized by its own
// l (identical code path to unsplit) + (m,l); B-half writes normalized partial
// to scratch + (m,l); combine kernel merges (R6/R13-proven algebra).
// Grid 1536 = 8 XCDs x 192; heavy-first; both halves provably have >=1
// unmasked stage (no exp2(NEG-NEG) poison).
__global__ __launch_bounds__(256, 4) void attn_kernel(
    const bf16* __restrict__ qb, const bf16* __restrict__ kb,
    const bf16* __restrict__ vt, bf16* __restrict__ ob,
    bf16* __restrict__ scrO, float* __restrict__ ml) {
  __shared__ bf16 Kl[2][64 * 64];  // [buf][kv-row][d-col swizzled]
  __shared__ bf16 Vl[2][64 * 64];  // [buf][d-row][kv-col swizzled]
  const int b = blockIdx.x;
  const int xcd = b & 7;
  const int idx = b >> 3;                    // 0..191
  int head, qt, st_lo, st_hi, role;          // role: 0=full, 1=A-half, 2=B-half
  if (idx < 128) {                           // split halves of qt 63..32, heavy-first
    qt = 63 - (idx >> 2);
    head = 2 * xcd + ((idx >> 1) & 1);
    const int hi = (qt + 2) >> 1;
    if ((idx & 1) == 0) { st_lo = 0; st_hi = hi; role = 1; }
    else                { st_lo = hi; st_hi = qt + 1; role = 2; }
  } else {                                   // light tiles qt 31..0
    const int j = idx - 128;
    qt = 31 - (j >> 1);
    head = 2 * xcd + (j & 1);
    st_lo = 0; st_hi = qt + 1; role = 0;
  }
  const int tid = threadIdx.x;
  const int w = tid >> 6, l = tid & 63;
  const int qc = l & 15, h = l >> 4;         // q-col within tile, lane group
  const int q0w = qt * 64 + w * 16;

  bf16x8 qf[2];  // B-frag: col q = q0w+qc, k(d) = c*32 + h*8 + i
  {
    const bf16* qp = qb + ((size_t)head * S + q0w + qc) * HD + h * 8;
    qf[0] = *reinterpret_cast<const bf16x8*>(qp);
    qf[1] = *reinterpret_cast<const bf16x8*>(qp + 32);
  }
  const bf16* kbase = kb + (size_t)head * S * HD;
  const bf16* vbase = vt + (size_t)head * HD * S;

  f32x4 acc[4];  // O^T: col q = qc, row d = 16*dt + 4*h + r
#pragma unroll
  for (int i = 0; i < 4; ++i) acc[i] = f32x4{0.f, 0.f, 0.f, 0.f};
  float mrun = NEG, lsum = 0.f;

  // staging: 256 threads x 2 granules each for K and V (16B granules)
  auto gload = [&](int st, bf16x8 (&kr)[2], bf16x8 (&vr)[2]) {
    const int kv0 = st * 64;
#pragma unroll
    for (int j = 0; j < 2; ++j) {
      const int g = tid + j * 256;
      const int row = g >> 3, ge = g & 7;
      kr[j] = *reinterpret_cast<const bf16x8*>(kbase + (size_t)(kv0 + row) * HD + ge * 8);
      vr[j] = *reinterpret_cast<const bf16x8*>(vbase + (size_t)row * S + kv0 + ge * 8);
    }
  };
  auto swrite = [&](int buf, bf16x8 (&kr)[2], bf16x8 (&vr)[2]) {
#pragma unroll
    for (int j = 0; j < 2; ++j) {
      const int g = tid + j * 256;
      const int row = g >> 3, ge = g & 7;
      const int off = row * 64 + ((ge * 8) ^ ((row & 7) << 3));
      *reinterpret_cast<bf16x8*>(&Kl[buf][off]) = kr[j];
      *reinterpret_cast<bf16x8*>(&Vl[buf][off]) = vr[j];
    }
  };

  {
    bf16x8 kr[2], vr[2];
    gload(st_lo, kr, vr);
    swrite(st_lo & 1, kr, vr);
  }
  __syncthreads();

  const int idxLo = ((2 * h) & 3) * 16 + qc;
  const int idxHi = ((2 * h + 1) & 3) * 16 + qc;

  for (int st = st_lo; st < st_hi; ++st) {
    const int buf = st & 1;
    const int kv0 = st * 64;
    const bool pre = (st + 1 < st_hi);
    bf16x8 kr[2], vr[2];
    if (pre) gload(st + 1, kr, vr);  // issue early; consumed by swrite at stage end

    if (kv0 <= q0w + 15) {  // skip fully-masked tiles (exact: contribution 0)
      // --- S^T[kv][q] = K @ Q from LDS: A-frag row kv=16t+qc, k(d)=c*32+h*8 ---
      f32x4 sv[4];
#pragma unroll
      for (int t = 0; t < 4; ++t) sv[t] = f32x4{0.f, 0.f, 0.f, 0.f};
      __builtin_amdgcn_s_setprio(1);
#pragma unroll
      for (int c = 0; c < 2; ++c)
#pragma unroll
        for (int t = 0; t < 4; ++t) {
          bf16x8 kf = *reinterpret_cast<const bf16x8*>(
              &Kl[buf][(16 * t + qc) * 64 + ((c * 32 + h * 8) ^ ((qc & 7) << 3))]);
          sv[t] = MFMA16(kf, qf[c], sv[t]);
        }
      __builtin_amdgcn_s_setprio(0);
      // --- causal mask: lane holds kv = kv0+16t+4h+r, q = q0w+qc ---
      if (kv0 + 63 > q0w) {
        const int q = q0w + qc;
#pragma unroll
        for (int t = 0; t < 4; ++t)
#pragma unroll
          for (int r = 0; r < 4; ++r)
            if (kv0 + 16 * t + 4 * h + r > q) sv[t][r] = NEG;
      }
      // --- online softmax (log2 domain, defer-max thr=8) ---
      float tmax = NEG;
#pragma unroll
      for (int t = 0; t < 4; ++t)
#pragma unroll
        for (int r = 0; r < 4; ++r) tmax = fmaxf(tmax, sv[t][r]);
      if (!__all(tmax <= mrun + 8.f)) {
        float tm = fmaxf(tmax, __shfl_xor(tmax, 16));
        tm = fmaxf(tm, __shfl_xor(tm, 32));
        float mnew = fmaxf(mrun, tm);
        float alpha = exp2f(mrun - mnew);
        lsum *= alpha;
#pragma unroll
        for (int dt = 0; dt < 4; ++dt)
#pragma unroll
          for (int r = 0; r < 4; ++r) acc[dt][r] *= alpha;
        mrun = mnew;
      }
      float psum = 0.f;
#pragma unroll
      for (int t = 0; t < 4; ++t)
#pragma unroll
        for (int r = 0; r < 4; ++r) {
          sv[t][r] = exp2f(sv[t][r] - mrun);
          psum += sv[t][r];
        }
      lsum += psum;
      // --- P -> bf16 pairs per subtile ---
      unsigned pk[4][2];
#pragma unroll
      for (int t = 0; t < 4; ++t) {
        union { unsigned u; bf16 h2[2]; } a, bqq;
        a.h2[0] = (bf16)sv[t][0]; a.h2[1] = (bf16)sv[t][1];
        bqq.h2[0] = (bf16)sv[t][2]; bqq.h2[1] = (bf16)sv[t][3];
        pk[t][0] = a.u; pk[t][1] = bqq.u;
      }
      // --- PV: per 32-kv chunk c2, assemble B-frag via shfl (rows 8h..8h+7, col qc) ---
#pragma unroll
      for (int c2 = 0; c2 < 2; ++c2) {
        const int tA = 2 * c2, tB = 2 * c2 + 1;
        unsigned s00 = (unsigned)__shfl((int)pk[tA][0], idxLo);
        unsigned s01 = (unsigned)__shfl((int)pk[tA][1], idxLo);
        unsigned s02 = (unsigned)__shfl((int)pk[tA][0], idxHi);
        unsigned s03 = (unsigned)__shfl((int)pk[tA][1], idxHi);
        unsigned s10 = (unsigned)__shfl((int)pk[tB][0], idxLo);
        unsigned s11 = (unsigned)__shfl((int)pk[tB][1], idxLo);
        unsigned s12 = (unsigned)__shfl((int)pk[tB][0], idxHi);
        unsigned s13 = (unsigned)__shfl((int)pk[tB][1], idxHi);
        const bool lo2 = (h < 2);
        union { bf16x8 v; unsigned u[4]; } B;
        B.u[0] = lo2 ? s00 : s10;
        B.u[1] = lo2 ? s01 : s11;
        B.u[2] = lo2 ? s02 : s12;
        B.u[3] = lo2 ? s03 : s13;
        __builtin_amdgcn_s_setprio(1);
#pragma unroll
        for (int dt = 0; dt < 4; ++dt) {
          bf16x8 vf = *reinterpret_cast<const bf16x8*>(
              &Vl[buf][(16 * dt + qc) * 64 + ((c2 * 32 + h * 8) ^ ((qc & 7) << 3))]);
          acc[dt] = MFMA16(vf, B.v, acc[dt]);
        }
        __builtin_amdgcn_s_setprio(0);
      }
    }
    // --- write next stage's tiles into the other buffer; lockstep barrier ---
    if (pre) swrite((st + 1) & 1, kr, vr);
    __syncthreads();
  }

  float lt = lsum + __shfl_xor(lsum, 16);
  lt += __shfl_xor(lt, 32);
  const float inv = 1.0f / lt;
  bf16* dst;
  if (role == 2) {
    const int tile = head * 32 + (qt - 32);
    dst = scrO + ((size_t)tile * 64 + w * 16 + qc) * 64;   // row-contig 64 d
  } else {
    dst = ob + (size_t)(q0w + qc) * E + head * HD;
  }
#pragma unroll
  for (int dt = 0; dt < 4; ++dt) {
    bf16x4 bb;
#pragma unroll
    for (int r = 0; r < 4; ++r) bb[r] = (bf16)(acc[dt][r] * inv);
    *reinterpret_cast<bf16x4*>(dst + 16 * dt + 4 * h) = bb;
  }
  if (role != 0 && h == 0) {  // one lane group per q-row records (m, l)
    const int tile = head * 32 + (qt - 32);
    float* mp = ml + (((size_t)(role - 1) * 512 + tile) * 64 + w * 16 + qc) * 2;
    mp[0] = mrun;
    mp[1] = lt;
  }
}

// ---------------- combine split-kv partials: ob = wA*obA' + wB*scrB' ----------------
__global__ __launch_bounds__(256) void combine_kernel(
    bf16* __restrict__ ob, const bf16* __restrict__ scrO,
    const float* __restrict__ ml) {
  const int r = blockIdx.x * 256 + threadIdx.x;  // 0..32767
  const int tile = r >> 6, row = r & 63;
  const int head = tile >> 5, q32 = tile & 31;
  const int qrow = (q32 + 32) * 64 + row;
  const float mA = ml[(size_t)tile * 128 + row * 2];
  const float lA = ml[(size_t)tile * 128 + row * 2 + 1];
  const float mB = ml[(size_t)(512 + tile) * 128 + row * 2];
  const float lB = ml[(size_t)(512 + tile) * 128 + row * 2 + 1];
  const float M = fmaxf(mA, mB);
  float wA = lA * exp2f(mA - M), wB = lB * exp2f(mB - M);
  const float s = 1.0f / (wA + wB);
  wA *= s; wB *= s;
  bf16* op = ob + (size_t)qrow * E + head * HD;
  const bf16* bp = scrO + (size_t)(tile * 64 + row) * 64;
#pragma unroll
  for (int i = 0; i < 8; ++i) {
    bf16x8 a = *reinterpret_cast<const bf16x8*>(op + i * 8);
    bf16x8 bb = *reinterpret_cast<const bf16x8*>(bp + i * 8);
    bf16x8 o;
#pragma unroll
    for (int j = 0; j < 8; ++j) o[j] = (bf16)(wA * (float)a[j] + wB * (float)bb[j]);
    *reinterpret_cast<bf16x8*>(op + i * 8) = o;
  }
}

// ---------------- output projection: out = attn @ wo^T (128x64 tiles, R10/R13-proven) ----------------
__global__ __launch_bounds__(256) void out_gemm_kernel(
    const bf16* __restrict__ ob, const bf16* __restrict__ wob,
    float* __restrict__ out) {
  const int w = threadIdx.x >> 6, l = threadIdx.x & 63, lg = l >> 4, lr = l & 15;
  const int s0 = blockIdx.x * 128, e0 = blockIdx.y * 64;
  f32x4 acc[2][4];
#pragma unroll
  for (int i = 0; i < 2; ++i)
#pragma unroll
    for (int jj = 0; jj < 4; ++jj) acc[i][jj] = f32x4{0.f, 0.f, 0.f, 0.f};
  const bf16* ap0 = ob + (size_t)(s0 + w * 16 + lr) * E;
  const bf16* ap1 = ap0 + (size_t)64 * E;
#pragma unroll 2
  for (int k = 0; k < E; k += 32) {
    bf16x8 a0 = *reinterpret_cast<const bf16x8*>(ap0 + k + lg * 8);
    bf16x8 a1 = *reinterpret_cast<const bf16x8*>(ap1 + k + lg * 8);
#pragma unroll
    for (int ct = 0; ct < 4; ++ct) {
      bf16x8 bfr = *reinterpret_cast<const bf16x8*>(
          wob + (size_t)(e0 + ct * 16 + lr) * E + k + lg * 8);
      acc[0][ct] = MFMA16(a0, bfr, acc[0][ct]);
      acc[1][ct] = MFMA16(a1, bfr, acc[1][ct]);
    }
  }
#pragma unroll
  for (int half = 0; half < 2; ++half)
#pragma unroll
    for (int ct = 0; ct < 4; ++ct)
#pragma unroll
      for (int r = 0; r < 4; ++r)
        out[(size_t)(s0 + half * 64 + w * 16 + lg * 4 + r) * E + e0 + ct * 16 + lr] =
            acc[half][ct][r];
}

extern "C" void kernel_launch(void* const* d_in, const int* in_sizes, int n_in,
                              void* d_out, int out_size, void* d_ws, size_t ws_size,
                              hipStream_t stream) {
  const float* x  = (const float*)d_in[0];
  const float* wq = (const float*)d_in[1];
  const float* wk = (const float*)d_in[2];
  const float* wv = (const float*)d_in[3];
  const float* wo = (const float*)d_in[4];
  float* out = (float*)d_out;

  bf16* qb   = (bf16*)d_ws;                      // [H][S][HD]  8 MB
  bf16* kb   = qb + (size_t)H * S * HD;          // [H][S][HD]  8 MB
  bf16* vt   = kb + (size_t)H * S * HD;          // [H][HD][S]  8 MB (V transposed)
  bf16* ob   = vt + (size_t)H * S * HD;          // [S][E]      8 MB
  bf16* wob  = ob + (size_t)S * E;               // [E][E]      2 MB
  bf16* scrO = wob + (size_t)E * E;              // [512][64][64] 4 MB (B partials)
  float* ml  = (float*)(scrO + (size_t)512 * 64 * 64);  // [2][512][64][2] 512 KB

  qkv_cvt_kernel<<<dim3(S / 64, H + 1), 256, 0, stream>>>(x, wq, wk, wv, wo, qb, kb, vt, wob);
  attn_kernel<<<dim3(1536), 256, 0, stream>>>(qb, kb, vt, ob, scrO, ml);
  combine_kernel<<<dim3(128), 256, 0, stream>>>(ob, scrO, ml);
  out_gemm_kernel<<<dim3(S / 128, E / 64), 256, 0, stream>>>(ob, wob, out);
}

// Round 19
// 152.164 us; speedup vs baseline: 1.1740x; 1.1740x over previous
//
#include <hip/hip_runtime.h>
#include <hip/hip_bf16.h>

typedef __bf16 bf16;
typedef __bf16 bf16x8 __attribute__((ext_vector_type(8)));
typedef __bf16 bf16x4 __attribute__((ext_vector_type(4)));
typedef float f32x4 __attribute__((ext_vector_type(4)));

#define MFMA16(a, b, c) __builtin_amdgcn_mfma_f32_16x16x32_bf16((a), (b), (c), 0, 0, 0)

constexpr int S = 4096;
constexpr int E = 1024;
constexpr int H = 16;
constexpr int HD = 64;
constexpr float NEG = -1e30f;
// scores in log2 domain: fold 1/sqrt(64) * log2(e) into Q
constexpr float QSCALE = 0.125f * 1.44269504088896f;

__device__ inline bf16x8 load_f32x8_as_bf16(const float* __restrict__ p) {
  float4 u0 = *reinterpret_cast<const float4*>(p);
  float4 u1 = *reinterpret_cast<const float4*>(p + 4);
  bf16x8 r;
  r[0] = (bf16)u0.x; r[1] = (bf16)u0.y; r[2] = (bf16)u0.z; r[3] = (bf16)u0.w;
  r[4] = (bf16)u1.x; r[5] = (bf16)u1.y; r[6] = (bf16)u1.z; r[7] = (bf16)u1.w;
  return r;
}

// ---------------- QKV projection (+ wo->bf16 folded in as blockIdx.y == 16) ----------------
// Q pre-scaled by QSCALE; V written TRANSPOSED: vt[h][d][s]
__global__ __launch_bounds__(256) void qkv_cvt_kernel(
    const float* __restrict__ x, const float* __restrict__ wq,
    const float* __restrict__ wk, const float* __restrict__ wv,
    const float* __restrict__ wo,
    bf16* __restrict__ qb, bf16* __restrict__ kb, bf16* __restrict__ vt,
    bf16* __restrict__ wob) {
  if (blockIdx.y == 16) {  // wo -> bf16 conversion lane
    for (int i = (blockIdx.x * 256 + threadIdx.x) * 4; i < E * E; i += 64 * 256 * 4) {
      float4 f = *reinterpret_cast<const float4*>(wo + i);
      bf16x4 b;
      b[0] = (bf16)f.x; b[1] = (bf16)f.y; b[2] = (bf16)f.z; b[3] = (bf16)f.w;
      *reinterpret_cast<bf16x4*>(wob + i) = b;
    }
    return;
  }
  const int h = blockIdx.y;
  const int s0 = blockIdx.x * 64;
  const int w = threadIdx.x >> 6;
  const int l = threadIdx.x & 63;
  const int lg = l >> 4, lr = l & 15;

  bf16x8 af[2];
  {
    const float* xp = x + (size_t)(s0 + w * 16 + lr) * E + h * HD;
    af[0] = load_f32x8_as_bf16(xp + lg * 8);
    af[1] = load_f32x8_as_bf16(xp + 32 + lg * 8);
  }
  const float* Wsrc[3] = {wq + (size_t)h * HD * HD, wk + (size_t)h * HD * HD,
                          wv + (size_t)h * HD * HD};
#pragma unroll
  for (int pj = 0; pj < 3; ++pj) {
    f32x4 acc[4];
#pragma unroll
    for (int ot = 0; ot < 4; ++ot) acc[ot] = f32x4{0.f, 0.f, 0.f, 0.f};
#pragma unroll
    for (int ks = 0; ks < 2; ++ks) {
#pragma unroll
      for (int ot = 0; ot < 4; ++ot) {
        bf16x8 bfr = load_f32x8_as_bf16(Wsrc[pj] + (size_t)(ot * 16 + lr) * HD + ks * 32 + lg * 8);
        acc[ot] = MFMA16(af[ks], bfr, acc[ot]);
      }
    }
    if (pj == 2) {
      // V^T store: vt[(h*HD + o)][s]
#pragma unroll
      for (int ot = 0; ot < 4; ++ot) {
        bf16x4 b;
#pragma unroll
        for (int r = 0; r < 4; ++r) b[r] = (bf16)acc[ot][r];
        *reinterpret_cast<bf16x4*>(vt + (size_t)(h * HD + ot * 16 + lr) * S +
                                   s0 + w * 16 + lg * 4) = b;
      }
    } else {
      const float scale = (pj == 0) ? QSCALE : 1.0f;
      bf16* op = ((pj == 0) ? qb : kb) + (size_t)h * S * HD;
#pragma unroll
      for (int ot = 0; ot < 4; ++ot)
#pragma unroll
        for (int r = 0; r < 4; ++r)
          op[(size_t)(s0 + w * 16 + lg * 4 + r) * HD + ot * 16 + lr] =
              (bf16)(acc[ot][r] * scale);
    }
  }
}

// ---------------- causal flash attention: MFMA16, 4 waves x 16 q-cols ----------------
// R17 structure. Changes vs R17 (both targeting per-stage pipe pressure):
// (1) P-exchange via v_permlane32_swap + v_permlane16_swap (pure VALU) --
//     removes 16 ds_bpermute + 8 selects per wave-stage from the DS pipe.
//     Derivation: x=pk[tA][r], y=pk[tB][r]; swap32: x'={Ag0,Ag1,Bg0,Bg1},
//     y'={Ag2,Ag3,Bg2,Bg3}; swap16 (odd16 of x <-> even16 of y):
//     x''={Ag0,Ag2,Bg0,Bg2}=B.u[0|1], y''={Ag1,Ag3,Bg1,Bg3}=B.u[2|3] --
//     matches R17's verified shfl mapping for all lane groups.
// (2) exp2 via raw v_exp_f32 (1 instr guaranteed).
__global__ __launch_bounds__(256, 4) void attn_kernel(
    const bf16* __restrict__ qb, const bf16* __restrict__ kb,
    const bf16* __restrict__ vt, bf16* __restrict__ ob) {
  __shared__ bf16 Kl[2][64 * 64];  // [buf][kv-row][d-col swizzled]
  __shared__ bf16 Vl[2][64 * 64];  // [buf][d-row][kv-col swizzled]
  const int b = blockIdx.x;
  const int xcd = b & 7;
  const int idx = b >> 3;                    // 0..127
  const int p = idx >> 1, hb = idx & 1;
  const int head = 2 * xcd + hb;
  const int qt = (p < 32) ? (hb ? p : 63 - p) : (hb ? 95 - p : p - 32);
  const int tid = threadIdx.x;
  const int w = tid >> 6, l = tid & 63;
  const int qc = l & 15, h = l >> 4;         // q-col within tile, lane group
  const int q0w = qt * 64 + w * 16;
  const int nst = qt + 1;                    // 64-kv stages, block-uniform

  bf16x8 qf[2];  // B-frag: col q = q0w+qc, k(d) = c*32 + h*8 + i
  {
    const bf16* qp = qb + ((size_t)head * S + q0w + qc) * HD + h * 8;
    qf[0] = *reinterpret_cast<const bf16x8*>(qp);
    qf[1] = *reinterpret_cast<const bf16x8*>(qp + 32);
  }
  const bf16* kbase = kb + (size_t)head * S * HD;
  const bf16* vbase = vt + (size_t)head * HD * S;

  f32x4 acc[4];  // O^T: col q = qc, row d = 16*dt + 4*h + r
#pragma unroll
  for (int i = 0; i < 4; ++i) acc[i] = f32x4{0.f, 0.f, 0.f, 0.f};
  float mrun = NEG, lsum = 0.f;

  // staging: 256 threads x 2 granules each for K and V (16B granules)
  auto gload = [&](int st, bf16x8 (&kr)[2], bf16x8 (&vr)[2]) {
    const int kv0 = st * 64;
#pragma unroll
    for (int j = 0; j < 2; ++j) {
      const int g = tid + j * 256;
      const int row = g >> 3, ge = g & 7;
      kr[j] = *reinterpret_cast<const bf16x8*>(kbase + (size_t)(kv0 + row) * HD + ge * 8);
      vr[j] = *reinterpret_cast<const bf16x8*>(vbase + (size_t)row * S + kv0 + ge * 8);
    }
  };
  auto swrite = [&](int buf, bf16x8 (&kr)[2], bf16x8 (&vr)[2]) {
#pragma unroll
    for (int j = 0; j < 2; ++j) {
      const int g = tid + j * 256;
      const int row = g >> 3, ge = g & 7;
      const int off = row * 64 + ((ge * 8) ^ ((row & 7) << 3));
      *reinterpret_cast<bf16x8*>(&Kl[buf][off]) = kr[j];
      *reinterpret_cast<bf16x8*>(&Vl[buf][off]) = vr[j];
    }
  };

  bf16x8 kr[2], vr[2];
  gload(0, kr, vr);
  swrite(0, kr, vr);
  __syncthreads();

  for (int st = 0; st < nst; ++st) {
    const int buf = st & 1;
    const int kv0 = st * 64;
    const bool pre = (st + 1 < nst);
    if (pre) gload(st + 1, kr, vr);  // issue early; consumed by swrite at stage end

    if (kv0 <= q0w + 15) {  // skip fully-masked tiles (exact: contribution 0)
      // --- S^T[kv][q] = K @ Q from LDS: A-frag row kv=16t+qc, k(d)=c*32+h*8 ---
      f32x4 sv[4];
#pragma unroll
      for (int t = 0; t < 4; ++t) sv[t] = f32x4{0.f, 0.f, 0.f, 0.f};
      __builtin_amdgcn_s_setprio(1);
#pragma unroll
      for (int c = 0; c < 2; ++c)
#pragma unroll
        for (int t = 0; t < 4; ++t) {
          bf16x8 kf = *reinterpret_cast<const bf16x8*>(
              &Kl[buf][(16 * t + qc) * 64 + ((c * 32 + h * 8) ^ ((qc & 7) << 3))]);
          sv[t] = MFMA16(kf, qf[c], sv[t]);
        }
      __builtin_amdgcn_s_setprio(0);
      // --- causal mask: lane holds kv = kv0+16t+4h+r, q = q0w+qc ---
      if (kv0 + 63 > q0w) {
        const int q = q0w + qc;
#pragma unroll
        for (int t = 0; t < 4; ++t)
#pragma unroll
          for (int r = 0; r < 4; ++r)
            if (kv0 + 16 * t + 4 * h + r > q) sv[t][r] = NEG;
      }
      // --- online softmax (log2 domain, defer-max thr=8) ---
      float tmax = NEG;
#pragma unroll
      for (int t = 0; t < 4; ++t)
#pragma unroll
        for (int r = 0; r < 4; ++r) tmax = fmaxf(tmax, sv[t][r]);
      if (!__all(tmax <= mrun + 8.f)) {
        float tm = fmaxf(tmax, __shfl_xor(tmax, 16));
        tm = fmaxf(tm, __shfl_xor(tm, 32));
        float mnew = fmaxf(mrun, tm);
        float alpha = exp2f(mrun - mnew);
        lsum *= alpha;
#pragma unroll
        for (int dt = 0; dt < 4; ++dt)
#pragma unroll
          for (int r = 0; r < 4; ++r) acc[dt][r] *= alpha;
        mrun = mnew;
      }
      float psum = 0.f;
#pragma unroll
      for (int t = 0; t < 4; ++t)
#pragma unroll
        for (int r = 0; r < 4; ++r) {
          float d = sv[t][r] - mrun;
          float e;
          asm("v_exp_f32 %0, %1" : "=v"(e) : "v"(d));  // D = 2^S0
          sv[t][r] = e;
          psum += e;
        }
      lsum += psum;
      // --- P -> bf16 pairs per subtile ---
      unsigned pk[4][2];
#pragma unroll
      for (int t = 0; t < 4; ++t) {
        union { unsigned u; bf16 h2[2]; } a, bqq;
        a.h2[0] = (bf16)sv[t][0]; a.h2[1] = (bf16)sv[t][1];
        bqq.h2[0] = (bf16)sv[t][2]; bqq.h2[1] = (bf16)sv[t][3];
        pk[t][0] = a.u; pk[t][1] = bqq.u;
      }
      // --- PV: B-frags via permlane32+permlane16 swaps (VALU-only exchange) ---
#pragma unroll
      for (int c2 = 0; c2 < 2; ++c2) {
        unsigned x0 = pk[2 * c2][0], y0 = pk[2 * c2 + 1][0];
        unsigned x1 = pk[2 * c2][1], y1 = pk[2 * c2 + 1][1];
        asm("v_permlane32_swap_b32 %0, %1" : "+v"(x0), "+v"(y0));
        asm("v_permlane16_swap_b32 %0, %1" : "+v"(x0), "+v"(y0));
        asm("v_permlane32_swap_b32 %0, %1" : "+v"(x1), "+v"(y1));
        asm("v_permlane16_swap_b32 %0, %1" : "+v"(x1), "+v"(y1));
        union { bf16x8 v; unsigned u[4]; } B;
        B.u[0] = x0; B.u[1] = x1; B.u[2] = y0; B.u[3] = y1;
        __builtin_amdgcn_s_setprio(1);
#pragma unroll
        for (int dt = 0; dt < 4; ++dt) {
          bf16x8 vf = *reinterpret_cast<const bf16x8*>(
              &Vl[buf][(16 * dt + qc) * 64 + ((c2 * 32 + h * 8) ^ ((qc & 7) << 3))]);
          acc[dt] = MFMA16(vf, B.v, acc[dt]);
        }
        __builtin_amdgcn_s_setprio(0);
      }
    }
    // --- write next stage's tiles into the other buffer; lockstep barrier ---
    if (pre) swrite(buf ^ 1, kr, vr);
    __syncthreads();
  }

  float lt = lsum + __shfl_xor(lsum, 16);
  lt += __shfl_xor(lt, 32);
  const float inv = 1.0f / lt;
  bf16* obp = ob + (size_t)(q0w + qc) * E + head * HD;
#pragma unroll
  for (int dt = 0; dt < 4; ++dt) {
    bf16x4 bb;
#pragma unroll
    for (int r = 0; r < 4; ++r) bb[r] = (bf16)(acc[dt][r] * inv);
    *reinterpret_cast<bf16x4*>(obp + 16 * dt + 4 * h) = bb;
  }
}

// ---------------- output projection: out = attn @ wo^T (128x64 tiles, R10/R13-proven) ----------------
__global__ __launch_bounds__(256) void out_gemm_kernel(
    const bf16* __restrict__ ob, const bf16* __restrict__ wob,
    float* __restrict__ out) {
  const int w = threadIdx.x >> 6, l = threadIdx.x & 63, lg = l >> 4, lr = l & 15;
  const int s0 = blockIdx.x * 128, e0 = blockIdx.y * 64;
  f32x4 acc[2][4];
#pragma unroll
  for (int i = 0; i < 2; ++i)
#pragma unroll
    for (int jj = 0; jj < 4; ++jj) acc[i][jj] = f32x4{0.f, 0.f, 0.f, 0.f};
  const bf16* ap0 = ob + (size_t)(s0 + w * 16 + lr) * E;
  const bf16* ap1 = ap0 + (size_t)64 * E;
#pragma unroll 2
  for (int k = 0; k < E; k += 32) {
    bf16x8 a0 = *reinterpret_cast<const bf16x8*>(ap0 + k + lg * 8);
    bf16x8 a1 = *reinterpret_cast<const bf16x8*>(ap1 + k + lg * 8);
#pragma unroll
    for (int ct = 0; ct < 4; ++ct) {
      bf16x8 bfr = *reinterpret_cast<const bf16x8*>(
          wob + (size_t)(e0 + ct * 16 + lr) * E + k + lg * 8);
      acc[0][ct] = MFMA16(a0, bfr, acc[0][ct]);
      acc[1][ct] = MFMA16(a1, bfr, acc[1][ct]);
    }
  }
#pragma unroll
  for (int half = 0; half < 2; ++half)
#pragma unroll
    for (int ct = 0; ct < 4; ++ct)
#pragma unroll
      for (int r = 0; r < 4; ++r)
        out[(size_t)(s0 + half * 64 + w * 16 + lg * 4 + r) * E + e0 + ct * 16 + lr] =
            acc[half][ct][r];
}

extern "C" void kernel_launch(void* const* d_in, const int* in_sizes, int n_in,
                              void* d_out, int out_size, void* d_ws, size_t ws_size,
                              hipStream_t stream) {
  const float* x  = (const float*)d_in[0];
  const float* wq = (const float*)d_in[1];
  const float* wk = (const float*)d_in[2];
  const float* wv = (const float*)d_in[3];
  const float* wo = (const float*)d_in[4];
  float* out = (float*)d_out;

  bf16* qb  = (bf16*)d_ws;                 // [H][S][HD]
  bf16* kb  = qb + (size_t)H * S * HD;     // [H][S][HD]
  bf16* vt  = kb + (size_t)H * S * HD;     // [H][HD][S]  (V transposed)
  bf16* ob  = vt + (size_t)H * S * HD;     // [S][E]
  bf16* wob = ob + (size_t)S * E;          // [E][E]

  qkv_cvt_kernel<<<dim3(S / 64, H + 1), 256, 0, stream>>>(x, wq, wk, wv, wo, qb, kb, vt, wob);
  attn_kernel<<<dim3(1024), 256, 0, stream>>>(qb, kb, vt, ob);
  out_gemm_kernel<<<dim3(S / 128, E / 64), 256, 0, stream>>>(ob, wob, out);
}

// Round 20
// 130.395 us; speedup vs baseline: 1.3700x; 1.1669x over previous
//
#include <hip/hip_runtime.h>
#include <hip/hip_bf16.h>

typedef __bf16 bf16;
typedef __bf16 bf16x8 __attribute__((ext_vector_type(8)));
typedef __bf16 bf16x4 __attribute__((ext_vector_type(4)));
typedef float f32x4 __attribute__((ext_vector_type(4)));

#define MFMA16(a, b, c) __builtin_amdgcn_mfma_f32_16x16x32_bf16((a), (b), (c), 0, 0, 0)

constexpr int S = 4096;
constexpr int E = 1024;
constexpr int H = 16;
constexpr int HD = 64;
constexpr float NEG = -1e30f;
// scores in log2 domain: fold 1/sqrt(64) * log2(e) into Q
constexpr float QSCALE = 0.125f * 1.44269504088896f;

__device__ inline bf16x8 load_f32x8_as_bf16(const float* __restrict__ p) {
  float4 u0 = *reinterpret_cast<const float4*>(p);
  float4 u1 = *reinterpret_cast<const float4*>(p + 4);
  bf16x8 r;
  r[0] = (bf16)u0.x; r[1] = (bf16)u0.y; r[2] = (bf16)u0.z; r[3] = (bf16)u0.w;
  r[4] = (bf16)u1.x; r[5] = (bf16)u1.y; r[6] = (bf16)u1.z; r[7] = (bf16)u1.w;
  return r;
}

// ---------------- QKV projection (+ wo->bf16 folded in as blockIdx.y == 16) ----------------
// Q pre-scaled by QSCALE; V written TRANSPOSED: vt[h][d][s]
__global__ __launch_bounds__(256) void qkv_cvt_kernel(
    const float* __restrict__ x, const float* __restrict__ wq,
    const float* __restrict__ wk, const float* __restrict__ wv,
    const float* __restrict__ wo,
    bf16* __restrict__ qb, bf16* __restrict__ kb, bf16* __restrict__ vt,
    bf16* __restrict__ wob) {
  if (blockIdx.y == 16) {  // wo -> bf16 conversion lane
    for (int i = (blockIdx.x * 256 + threadIdx.x) * 4; i < E * E; i += 64 * 256 * 4) {
      float4 f = *reinterpret_cast<const float4*>(wo + i);
      bf16x4 b;
      b[0] = (bf16)f.x; b[1] = (bf16)f.y; b[2] = (bf16)f.z; b[3] = (bf16)f.w;
      *reinterpret_cast<bf16x4*>(wob + i) = b;
    }
    return;
  }
  const int h = blockIdx.y;
  const int s0 = blockIdx.x * 64;
  const int w = threadIdx.x >> 6;
  const int l = threadIdx.x & 63;
  const int lg = l >> 4, lr = l & 15;

  bf16x8 af[2];
  {
    const float* xp = x + (size_t)(s0 + w * 16 + lr) * E + h * HD;
    af[0] = load_f32x8_as_bf16(xp + lg * 8);
    af[1] = load_f32x8_as_bf16(xp + 32 + lg * 8);
  }
  const float* Wsrc[3] = {wq + (size_t)h * HD * HD, wk + (size_t)h * HD * HD,
                          wv + (size_t)h * HD * HD};
#pragma unroll
  for (int pj = 0; pj < 3; ++pj) {
    f32x4 acc[4];
#pragma unroll
    for (int ot = 0; ot < 4; ++ot) acc[ot] = f32x4{0.f, 0.f, 0.f, 0.f};
#pragma unroll
    for (int ks = 0; ks < 2; ++ks) {
#pragma unroll
      for (int ot = 0; ot < 4; ++ot) {
        bf16x8 bfr = load_f32x8_as_bf16(Wsrc[pj] + (size_t)(ot * 16 + lr) * HD + ks * 32 + lg * 8);
        acc[ot] = MFMA16(af[ks], bfr, acc[ot]);
      }
    }
    if (pj == 2) {
      // V^T store: vt[(h*HD + o)][s]
#pragma unroll
      for (int ot = 0; ot < 4; ++ot) {
        bf16x4 b;
#pragma unroll
        for (int r = 0; r < 4; ++r) b[r] = (bf16)acc[ot][r];
        *reinterpret_cast<bf16x4*>(vt + (size_t)(h * HD + ot * 16 + lr) * S +
                                   s0 + w * 16 + lg * 4) = b;
      }
    } else {
      const float scale = (pj == 0) ? QSCALE : 1.0f;
      bf16* op = ((pj == 0) ? qb : kb) + (size_t)h * S * HD;
#pragma unroll
      for (int ot = 0; ot < 4; ++ot)
#pragma unroll
        for (int r = 0; r < 4; ++r)
          op[(size_t)(s0 + w * 16 + lg * 4 + r) * HD + ot * 16 + lr] =
              (bf16)(acc[ot][r] * scale);
    }
  }
}

// ---------------- causal flash attention: MFMA16, 4 waves x 16 q-cols (R19-verified) ----------------
__global__ __launch_bounds__(256, 4) void attn_kernel(
    const bf16* __restrict__ qb, const bf16* __restrict__ kb,
    const bf16* __restrict__ vt, bf16* __restrict__ ob) {
  __shared__ bf16 Kl[2][64 * 64];  // [buf][kv-row][d-col swizzled]
  __shared__ bf16 Vl[2][64 * 64];  // [buf][d-row][kv-col swizzled]
  const int b = blockIdx.x;
  const int xcd = b & 7;
  const int idx = b >> 3;                    // 0..127
  const int p = idx >> 1, hb = idx & 1;
  const int head = 2 * xcd + hb;
  const int qt = (p < 32) ? (hb ? p : 63 - p) : (hb ? 95 - p : p - 32);
  const int tid = threadIdx.x;
  const int w = tid >> 6, l = tid & 63;
  const int qc = l & 15, h = l >> 4;         // q-col within tile, lane group
  const int q0w = qt * 64 + w * 16;
  const int nst = qt + 1;                    // 64-kv stages, block-uniform

  bf16x8 qf[2];  // B-frag: col q = q0w+qc, k(d) = c*32 + h*8 + i
  {
    const bf16* qp = qb + ((size_t)head * S + q0w + qc) * HD + h * 8;
    qf[0] = *reinterpret_cast<const bf16x8*>(qp);
    qf[1] = *reinterpret_cast<const bf16x8*>(qp + 32);
  }
  const bf16* kbase = kb + (size_t)head * S * HD;
  const bf16* vbase = vt + (size_t)head * HD * S;

  f32x4 acc[4];  // O^T: col q = qc, row d = 16*dt + 4*h + r
#pragma unroll
  for (int i = 0; i < 4; ++i) acc[i] = f32x4{0.f, 0.f, 0.f, 0.f};
  float mrun = NEG, lsum = 0.f;

  // staging: 256 threads x 2 granules each for K and V (16B granules)
  auto gload = [&](int st, bf16x8 (&kr)[2], bf16x8 (&vr)[2]) {
    const int kv0 = st * 64;
#pragma unroll
    for (int j = 0; j < 2; ++j) {
      const int g = tid + j * 256;
      const int row = g >> 3, ge = g & 7;
      kr[j] = *reinterpret_cast<const bf16x8*>(kbase + (size_t)(kv0 + row) * HD + ge * 8);
      vr[j] = *reinterpret_cast<const bf16x8*>(vbase + (size_t)row * S + kv0 + ge * 8);
    }
  };
  auto swrite = [&](int buf, bf16x8 (&kr)[2], bf16x8 (&vr)[2]) {
#pragma unroll
    for (int j = 0; j < 2; ++j) {
      const int g = tid + j * 256;
      const int row = g >> 3, ge = g & 7;
      const int off = row * 64 + ((ge * 8) ^ ((row & 7) << 3));
      *reinterpret_cast<bf16x8*>(&Kl[buf][off]) = kr[j];
      *reinterpret_cast<bf16x8*>(&Vl[buf][off]) = vr[j];
    }
  };

  bf16x8 kr[2], vr[2];
  gload(0, kr, vr);
  swrite(0, kr, vr);
  __syncthreads();

  for (int st = 0; st < nst; ++st) {
    const int buf = st & 1;
    const int kv0 = st * 64;
    const bool pre = (st + 1 < nst);
    if (pre) gload(st + 1, kr, vr);  // issue early; consumed by swrite at stage end

    if (kv0 <= q0w + 15) {  // skip fully-masked tiles (exact: contribution 0)
      // --- S^T[kv][q] = K @ Q from LDS: A-frag row kv=16t+qc, k(d)=c*32+h*8 ---
      f32x4 sv[4];
#pragma unroll
      for (int t = 0; t < 4; ++t) sv[t] = f32x4{0.f, 0.f, 0.f, 0.f};
      __builtin_amdgcn_s_setprio(1);
#pragma unroll
      for (int c = 0; c < 2; ++c)
#pragma unroll
        for (int t = 0; t < 4; ++t) {
          bf16x8 kf = *reinterpret_cast<const bf16x8*>(
              &Kl[buf][(16 * t + qc) * 64 + ((c * 32 + h * 8) ^ ((qc & 7) << 3))]);
          sv[t] = MFMA16(kf, qf[c], sv[t]);
        }
      __builtin_amdgcn_s_setprio(0);
      // --- causal mask: lane holds kv = kv0+16t+4h+r, q = q0w+qc ---
      if (kv0 + 63 > q0w) {
        const int q = q0w + qc;
#pragma unroll
        for (int t = 0; t < 4; ++t)
#pragma unroll
          for (int r = 0; r < 4; ++r)
            if (kv0 + 16 * t + 4 * h + r > q) sv[t][r] = NEG;
      }
      // --- online softmax (log2 domain, defer-max thr=8) ---
      float tmax = NEG;
#pragma unroll
      for (int t = 0; t < 4; ++t)
#pragma unroll
        for (int r = 0; r < 4; ++r) tmax = fmaxf(tmax, sv[t][r]);
      if (!__all(tmax <= mrun + 8.f)) {
        float tm = fmaxf(tmax, __shfl_xor(tmax, 16));
        tm = fmaxf(tm, __shfl_xor(tm, 32));
        float mnew = fmaxf(mrun, tm);
        float alpha = exp2f(mrun - mnew);
        lsum *= alpha;
#pragma unroll
        for (int dt = 0; dt < 4; ++dt)
#pragma unroll
          for (int r = 0; r < 4; ++r) acc[dt][r] *= alpha;
        mrun = mnew;
      }
      float psum = 0.f;
#pragma unroll
      for (int t = 0; t < 4; ++t)
#pragma unroll
        for (int r = 0; r < 4; ++r) {
          float d = sv[t][r] - mrun;
          float e;
          asm("v_exp_f32 %0, %1" : "=v"(e) : "v"(d));  // D = 2^S0
          sv[t][r] = e;
          psum += e;
        }
      lsum += psum;
      // --- P -> bf16 pairs per subtile ---
      unsigned pk[4][2];
#pragma unroll
      for (int t = 0; t < 4; ++t) {
        union { unsigned u; bf16 h2[2]; } a, bqq;
        a.h2[0] = (bf16)sv[t][0]; a.h2[1] = (bf16)sv[t][1];
        bqq.h2[0] = (bf16)sv[t][2]; bqq.h2[1] = (bf16)sv[t][3];
        pk[t][0] = a.u; pk[t][1] = bqq.u;
      }
      // --- PV: B-frags via permlane32+permlane16 swaps (VALU-only exchange) ---
#pragma unroll
      for (int c2 = 0; c2 < 2; ++c2) {
        unsigned x0 = pk[2 * c2][0], y0 = pk[2 * c2 + 1][0];
        unsigned x1 = pk[2 * c2][1], y1 = pk[2 * c2 + 1][1];
        asm("v_permlane32_swap_b32 %0, %1" : "+v"(x0), "+v"(y0));
        asm("v_permlane16_swap_b32 %0, %1" : "+v"(x0), "+v"(y0));
        asm("v_permlane32_swap_b32 %0, %1" : "+v"(x1), "+v"(y1));
        asm("v_permlane16_swap_b32 %0, %1" : "+v"(x1), "+v"(y1));
        union { bf16x8 v; unsigned u[4]; } B;
        B.u[0] = x0; B.u[1] = x1; B.u[2] = y0; B.u[3] = y1;
        __builtin_amdgcn_s_setprio(1);
#pragma unroll
        for (int dt = 0; dt < 4; ++dt) {
          bf16x8 vf = *reinterpret_cast<const bf16x8*>(
              &Vl[buf][(16 * dt + qc) * 64 + ((c2 * 32 + h * 8) ^ ((qc & 7) << 3))]);
          acc[dt] = MFMA16(vf, B.v, acc[dt]);
        }
        __builtin_amdgcn_s_setprio(0);
      }
    }
    // --- write next stage's tiles into the other buffer; lockstep barrier ---
    if (pre) swrite(buf ^ 1, kr, vr);
    __syncthreads();
  }

  float lt = lsum + __shfl_xor(lsum, 16);
  lt += __shfl_xor(lt, 32);
  const float inv = 1.0f / lt;
  bf16* obp = ob + (size_t)(q0w + qc) * E + head * HD;
#pragma unroll
  for (int dt = 0; dt < 4; ++dt) {
    bf16x4 bb;
#pragma unroll
    for (int r = 0; r < 4; ++r) bb[r] = (bf16)(acc[dt][r] * inv);
    *reinterpret_cast<bf16x4*>(obp + 16 * dt + 4 * h) = bb;
  }
}

// ---------------- output projection: out = attn @ wo^T, 128x128 tiles, B in LDS ----------------
// 256 blocks (1/CU). B tile (128 cols x 64 k, 16 KB) staged once per block per
// k-step into dbuf LDS with the attn-verified conflict-free layout
// (64-elem rows, elem ^= (row&7)<<3). Per iter/wave: 4 A loads + 16 LDS reads
// + 32 MFMA (2x the MFMA:load ratio of the old 128x64 version, 8x fewer
// global B bytes). gload-early / swrite-late / 1 barrier per iter.
__global__ __launch_bounds__(256) void out_gemm_kernel(
    const bf16* __restrict__ ob, const bf16* __restrict__ wob,
    float* __restrict__ out) {
  __shared__ bf16 Bl[2][128 * 64];  // [buf][col*64 + swizzled kk]  (2 x 16 KB)
  const int tid = threadIdx.x;
  const int w = tid >> 6, l = tid & 63, lg = l >> 4, lr = l & 15;
  const int s0 = blockIdx.x * 128, e0 = blockIdx.y * 128;
  f32x4 acc[2][8];
#pragma unroll
  for (int rt = 0; rt < 2; ++rt)
#pragma unroll
    for (int ct = 0; ct < 8; ++ct) acc[rt][ct] = f32x4{0.f, 0.f, 0.f, 0.f};
  const bf16* ap0 = ob + (size_t)(s0 + w * 32 + lr) * E;
  const bf16* ap1 = ap0 + (size_t)16 * E;

  // staging: 256 threads x 4 granules (16B): col = g>>3 (0..127), ge = g&7 (k-chunk)
  auto gloadB = [&](int k0, bf16x8 (&br)[4]) {
#pragma unroll
    for (int j = 0; j < 4; ++j) {
      const int g = tid + j * 256;
      const int col = g >> 3, ge = g & 7;
      br[j] = *reinterpret_cast<const bf16x8*>(wob + (size_t)(e0 + col) * E + k0 + ge * 8);
    }
  };
  auto swriteB = [&](int buf, bf16x8 (&br)[4]) {
#pragma unroll
    for (int j = 0; j < 4; ++j) {
      const int g = tid + j * 256;
      const int col = g >> 3, ge = g & 7;
      *reinterpret_cast<bf16x8*>(&Bl[buf][col * 64 + ((ge * 8) ^ ((col & 7) << 3))]) = br[j];
    }
  };

  bf16x8 br[4];
  gloadB(0, br);
  swriteB(0, br);
  __syncthreads();

  for (int it = 0; it < 16; ++it) {
    const int k0 = it * 64;
    const int buf = it & 1;
    const bool pre = (it + 1 < 16);
    if (pre) gloadB(k0 + 64, br);  // issue early; landed by swriteB at iter end

    bf16x8 af[2][2];
#pragma unroll
    for (int ks = 0; ks < 2; ++ks) {
      af[0][ks] = *reinterpret_cast<const bf16x8*>(ap0 + k0 + ks * 32 + lg * 8);
      af[1][ks] = *reinterpret_cast<const bf16x8*>(ap1 + k0 + ks * 32 + lg * 8);
    }
#pragma unroll
    for (int ks = 0; ks < 2; ++ks)
#pragma unroll
      for (int ct = 0; ct < 8; ++ct) {
        bf16x8 bfr = *reinterpret_cast<const bf16x8*>(
            &Bl[buf][(ct * 16 + lr) * 64 + ((ks * 32 + lg * 8) ^ ((lr & 7) << 3))]);
        acc[0][ct] = MFMA16(af[0][ks], bfr, acc[0][ct]);
        acc[1][ct] = MFMA16(af[1][ks], bfr, acc[1][ct]);
      }
    if (pre) swriteB(buf ^ 1, br);
    __syncthreads();
  }

#pragma unroll
  for (int rt = 0; rt < 2; ++rt)
#pragma unroll
    for (int ct = 0; ct < 8; ++ct)
#pragma unroll
      for (int r = 0; r < 4; ++r)
        out[(size_t)(s0 + w * 32 + rt * 16 + lg * 4 + r) * E + e0 + ct * 16 + lr] =
            acc[rt][ct][r];
}

extern "C" void kernel_launch(void* const* d_in, const int* in_sizes, int n_in,
                              void* d_out, int out_size, void* d_ws, size_t ws_size,
                              hipStream_t stream) {
  const float* x  = (const float*)d_in[0];
  const float* wq = (const float*)d_in[1];
  const float* wk = (const float*)d_in[2];
  const float* wv = (const float*)d_in[3];
  const float* wo = (const float*)d_in[4];
  float* out = (float*)d_out;

  bf16* qb  = (bf16*)d_ws;                 // [H][S][HD]
  bf16* kb  = qb + (size_t)H * S * HD;     // [H][S][HD]
  bf16* vt  = kb + (size_t)H * S * HD;     // [H][HD][S]  (V transposed)
  bf16* ob  = vt + (size_t)H * S * HD;     // [S][E]
  bf16* wob = ob + (size_t)S * E;          // [E][E]

  qkv_cvt_kernel<<<dim3(S / 64, H + 1), 256, 0, stream>>>(x, wq, wk, wv, wo, qb, kb, vt, wob);
  attn_kernel<<<dim3(1024), 256, 0, stream>>>(qb, kb, vt, ob);
  out_gemm_kernel<<<dim3(S / 128, E / 128), 256, 0, stream>>>(ob, wob, out);
}

// Round 21
// 125.228 us; speedup vs baseline: 1.4265x; 1.0413x over previous
//
#include <hip/hip_runtime.h>
#include <hip/hip_bf16.h>

typedef __bf16 bf16;
typedef __bf16 bf16x8 __attribute__((ext_vector_type(8)));
typedef __bf16 bf16x4 __attribute__((ext_vector_type(4)));
typedef float f32x4 __attribute__((ext_vector_type(4)));

#define MFMA16(a, b, c) __builtin_amdgcn_mfma_f32_16x16x32_bf16((a), (b), (c), 0, 0, 0)

constexpr int S = 4096;
constexpr int E = 1024;
constexpr int H = 16;
constexpr int HD = 64;
constexpr float NEG = -1e30f;
// scores in log2 domain: fold 1/sqrt(64) * log2(e) into Q
constexpr float QSCALE = 0.125f * 1.44269504088896f;

__device__ inline bf16x8 load_f32x8_as_bf16(const float* __restrict__ p) {
  float4 u0 = *reinterpret_cast<const float4*>(p);
  float4 u1 = *reinterpret_cast<const float4*>(p + 4);
  bf16x8 r;
  r[0] = (bf16)u0.x; r[1] = (bf16)u0.y; r[2] = (bf16)u0.z; r[3] = (bf16)u0.w;
  r[4] = (bf16)u1.x; r[5] = (bf16)u1.y; r[6] = (bf16)u1.z; r[7] = (bf16)u1.w;
  return r;
}

// ---------------- QKV projection (+ wo->bf16 folded in as blockIdx.y == 16) ----------------
// Q pre-scaled by QSCALE; V written TRANSPOSED: vt[h][d][s]
__global__ __launch_bounds__(256) void qkv_cvt_kernel(
    const float* __restrict__ x, const float* __restrict__ wq,
    const float* __restrict__ wk, const float* __restrict__ wv,
    const float* __restrict__ wo,
    bf16* __restrict__ qb, bf16* __restrict__ kb, bf16* __restrict__ vt,
    bf16* __restrict__ wob) {
  if (blockIdx.y == 16) {  // wo -> bf16 conversion lane
    for (int i = (blockIdx.x * 256 + threadIdx.x) * 4; i < E * E; i += 64 * 256 * 4) {
      float4 f = *reinterpret_cast<const float4*>(wo + i);
      bf16x4 b;
      b[0] = (bf16)f.x; b[1] = (bf16)f.y; b[2] = (bf16)f.z; b[3] = (bf16)f.w;
      *reinterpret_cast<bf16x4*>(wob + i) = b;
    }
    return;
  }
  const int h = blockIdx.y;
  const int s0 = blockIdx.x * 64;
  const int w = threadIdx.x >> 6;
  const int l = threadIdx.x & 63;
  const int lg = l >> 4, lr = l & 15;

  bf16x8 af[2];
  {
    const float* xp = x + (size_t)(s0 + w * 16 + lr) * E + h * HD;
    af[0] = load_f32x8_as_bf16(xp + lg * 8);
    af[1] = load_f32x8_as_bf16(xp + 32 + lg * 8);
  }
  const float* Wsrc[3] = {wq + (size_t)h * HD * HD, wk + (size_t)h * HD * HD,
                          wv + (size_t)h * HD * HD};
#pragma unroll
  for (int pj = 0; pj < 3; ++pj) {
    f32x4 acc[4];
#pragma unroll
    for (int ot = 0; ot < 4; ++ot) acc[ot] = f32x4{0.f, 0.f, 0.f, 0.f};
#pragma unroll
    for (int ks = 0; ks < 2; ++ks) {
#pragma unroll
      for (int ot = 0; ot < 4; ++ot) {
        bf16x8 bfr = load_f32x8_as_bf16(Wsrc[pj] + (size_t)(ot * 16 + lr) * HD + ks * 32 + lg * 8);
        acc[ot] = MFMA16(af[ks], bfr, acc[ot]);
      }
    }
    if (pj == 2) {
      // V^T store: vt[(h*HD + o)][s]
#pragma unroll
      for (int ot = 0; ot < 4; ++ot) {
        bf16x4 b;
#pragma unroll
        for (int r = 0; r < 4; ++r) b[r] = (bf16)acc[ot][r];
        *reinterpret_cast<bf16x4*>(vt + (size_t)(h * HD + ot * 16 + lr) * S +
                                   s0 + w * 16 + lg * 4) = b;
      }
    } else {
      const float scale = (pj == 0) ? QSCALE : 1.0f;
      bf16* op = ((pj == 0) ? qb : kb) + (size_t)h * S * HD;
#pragma unroll
      for (int ot = 0; ot < 4; ++ot)
#pragma unroll
        for (int r = 0; r < 4; ++r)
          op[(size_t)(s0 + w * 16 + lg * 4 + r) * HD + ot * 16 + lr] =
              (bf16)(acc[ot][r] * scale);
    }
  }
}

// ---------------- causal flash attention: MFMA16, 2-D wave split (32q x 32kv) ----------------
// Block = 64 q x 16 heads tile as before, but wave (i,j) owns q-half i (32 q,
// 2 q-tiles) x kv-half j (32 kv) of each 64-kv stage -> per wave-stage DS reads
// drop 16->8 b128 (K 4, V 4; each wave touches only its kv-half) while
// S-elements/wave-stage stay 1024. kv-halves keep independent (m,l,acc) merged
// exactly at the end through the dead K/V LDS (R13-proven algebra,
// unnormalized partials; skipped waves contribute exp2(NEG-M)=0).
// P-exchange per q-tile = R19-verified permlane pattern on subtile pair.
__global__ __launch_bounds__(256, 4) void attn_kernel(
    const bf16* __restrict__ qb, const bf16* __restrict__ kb,
    const bf16* __restrict__ vt, bf16* __restrict__ ob) {
  __shared__ bf16 Kl[2][64 * 64];  // [buf][kv-row][d-col swizzled]; epilogue: acc merge (4096 f32)
  __shared__ bf16 Vl[2][64 * 64];  // [buf][d-row][kv-col swizzled]; epilogue: (m,l) slots
  const int b = blockIdx.x;
  const int xcd = b & 7;
  const int idx = b >> 3;                    // 0..127
  const int p = idx >> 1, hb = idx & 1;
  const int head = 2 * xcd + hb;
  const int qt = (p < 32) ? (hb ? p : 63 - p) : (hb ? 95 - p : p - 32);
  const int tid = threadIdx.x;
  const int w = tid >> 6, l = tid & 63;
  const int qc = l & 15, h = l >> 4;         // q-col in tile, lane group
  const int i = w & 1, j = w >> 1;           // q-half, kv-half
  const int j32 = j * 32;
  const int q0w = qt * 64 + i * 32;
  const int nst = qt + 1;                    // 64-kv stages, block-uniform
  const int sw = (qc & 7) << 3;              // XOR swizzle (row&7 == qc&7 for all rows used)

  bf16x8 qf[2][2];  // [u][c]: col q = q0w + u*16 + qc, k(d) = c*32 + h*8 + ii
  {
    const bf16* qp = qb + ((size_t)head * S + q0w + qc) * HD + h * 8;
    qf[0][0] = *reinterpret_cast<const bf16x8*>(qp);
    qf[0][1] = *reinterpret_cast<const bf16x8*>(qp + 32);
    qf[1][0] = *reinterpret_cast<const bf16x8*>(qp + 16 * HD);
    qf[1][1] = *reinterpret_cast<const bf16x8*>(qp + 16 * HD + 32);
  }
  const bf16* kbase = kb + (size_t)head * S * HD;
  const bf16* vbase = vt + (size_t)head * HD * S;

  f32x4 acc[2][4];  // [u][dt]: O^T col q = (u,qc), row d = 16*dt + 4*h + r
#pragma unroll
  for (int u = 0; u < 2; ++u)
#pragma unroll
    for (int dt = 0; dt < 4; ++dt) acc[u][dt] = f32x4{0.f, 0.f, 0.f, 0.f};
  float m0 = NEG, m1 = NEG, l0 = 0.f, l1 = 0.f;

  // staging: 256 threads x 2 granules each for K and V (16B granules)
  auto gload = [&](int st, bf16x8 (&kr)[2], bf16x8 (&vr)[2]) {
    const int kv0 = st * 64;
#pragma unroll
    for (int jj = 0; jj < 2; ++jj) {
      const int g = tid + jj * 256;
      const int row = g >> 3, ge = g & 7;
      kr[jj] = *reinterpret_cast<const bf16x8*>(kbase + (size_t)(kv0 + row) * HD + ge * 8);
      vr[jj] = *reinterpret_cast<const bf16x8*>(vbase + (size_t)row * S + kv0 + ge * 8);
    }
  };
  auto swrite = [&](int buf, bf16x8 (&kr)[2], bf16x8 (&vr)[2]) {
#pragma unroll
    for (int jj = 0; jj < 2; ++jj) {
      const int g = tid + jj * 256;
      const int row = g >> 3, ge = g & 7;
      const int off = row * 64 + ((ge * 8) ^ ((row & 7) << 3));
      *reinterpret_cast<bf16x8*>(&Kl[buf][off]) = kr[jj];
      *reinterpret_cast<bf16x8*>(&Vl[buf][off]) = vr[jj];
    }
  };

  bf16x8 kr[2], vr[2];
  gload(0, kr, vr);
  swrite(0, kr, vr);
  __syncthreads();

  for (int st = 0; st < nst; ++st) {
    const int buf = st & 1;
    const int kv0 = st * 64;
    const bool pre = (st + 1 < nst);
    if (pre) gload(st + 1, kr, vr);  // issue early; consumed by swrite at stage end

    if (kv0 + j32 <= q0w + 31) {  // wave's kv chunk fully masked? skip (exact)
      // --- S^T: A-frag = K rows (j32+16t+qc), k(d)=c*32+h*8 -> 4 LDS reads ---
      bf16x8 kf[2][2];
#pragma unroll
      for (int t = 0; t < 2; ++t)
#pragma unroll
        for (int c = 0; c < 2; ++c)
          kf[t][c] = *reinterpret_cast<const bf16x8*>(
              &Kl[buf][(j32 + 16 * t + qc) * 64 + ((c * 32 + h * 8) ^ sw)]);
      f32x4 sv[2][2];  // [u][t]
      __builtin_amdgcn_s_setprio(1);
#pragma unroll
      for (int u = 0; u < 2; ++u)
#pragma unroll
        for (int t = 0; t < 2; ++t) {
          f32x4 a = f32x4{0.f, 0.f, 0.f, 0.f};
          a = MFMA16(kf[t][0], qf[u][0], a);
          a = MFMA16(kf[t][1], qf[u][1], a);
          sv[u][t] = a;
        }
      __builtin_amdgcn_s_setprio(0);
      // --- V frags for PV (4 reads, shared across both u) ---
      bf16x8 vf[4];
#pragma unroll
      for (int dt = 0; dt < 4; ++dt)
        vf[dt] = *reinterpret_cast<const bf16x8*>(
            &Vl[buf][(16 * dt + qc) * 64 + ((j32 + h * 8) ^ sw)]);
      // --- causal mask: kv = kv0+j32+16t+4h+r vs q = q0w+u*16+qc ---
      if (kv0 + 63 > q0w) {
#pragma unroll
        for (int u = 0; u < 2; ++u) {
          const int q = q0w + u * 16 + qc;
#pragma unroll
          for (int t = 0; t < 2; ++t)
#pragma unroll
            for (int r = 0; r < 4; ++r)
              if (kv0 + j32 + 16 * t + 4 * h + r > q) sv[u][t][r] = NEG;
        }
      }
      // --- online softmax (log2 domain, defer-max thr=8), per q-half u ---
      float t0 = NEG, t1 = NEG;
#pragma unroll
      for (int t = 0; t < 2; ++t)
#pragma unroll
        for (int r = 0; r < 4; ++r) {
          t0 = fmaxf(t0, sv[0][t][r]);
          t1 = fmaxf(t1, sv[1][t][r]);
        }
      if (!__all((t0 <= m0 + 8.f) && (t1 <= m1 + 8.f))) {
        float a0 = fmaxf(t0, __shfl_xor(t0, 16));
        a0 = fmaxf(a0, __shfl_xor(a0, 32));
        float a1 = fmaxf(t1, __shfl_xor(t1, 16));
        a1 = fmaxf(a1, __shfl_xor(a1, 32));
        float mn0 = fmaxf(m0, a0), mn1 = fmaxf(m1, a1);
        float al0 = exp2f(m0 - mn0), al1 = exp2f(m1 - mn1);
        l0 *= al0; l1 *= al1;
#pragma unroll
        for (int dt = 0; dt < 4; ++dt)
#pragma unroll
          for (int r = 0; r < 4; ++r) {
            acc[0][dt][r] *= al0;
            acc[1][dt][r] *= al1;
          }
        m0 = mn0; m1 = mn1;
      }
      float p0 = 0.f, p1 = 0.f;
#pragma unroll
      for (int t = 0; t < 2; ++t)
#pragma unroll
        for (int r = 0; r < 4; ++r) {
          float d0 = sv[0][t][r] - m0, e0;
          asm("v_exp_f32 %0, %1" : "=v"(e0) : "v"(d0));
          sv[0][t][r] = e0; p0 += e0;
          float d1 = sv[1][t][r] - m1, e1;
          asm("v_exp_f32 %0, %1" : "=v"(e1) : "v"(d1));
          sv[1][t][r] = e1; p1 += e1;
        }
      l0 += p0; l1 += p1;
      // --- P->bf16, permlane exchange (R19 mapping, per u), PV ---
#pragma unroll
      for (int u = 0; u < 2; ++u) {
        union { unsigned u32; bf16 h2[2]; } pa, pb;
        unsigned x0, x1, y0, y1;
        pa.h2[0] = (bf16)sv[u][0][0]; pa.h2[1] = (bf16)sv[u][0][1]; x0 = pa.u32;
        pb.h2[0] = (bf16)sv[u][0][2]; pb.h2[1] = (bf16)sv[u][0][3]; x1 = pb.u32;
        pa.h2[0] = (bf16)sv[u][1][0]; pa.h2[1] = (bf16)sv[u][1][1]; y0 = pa.u32;
        pb.h2[0] = (bf16)sv[u][1][2]; pb.h2[1] = (bf16)sv[u][1][3]; y1 = pb.u32;
        asm("v_permlane32_swap_b32 %0, %1" : "+v"(x0), "+v"(y0));
        asm("v_permlane16_swap_b32 %0, %1" : "+v"(x0), "+v"(y0));
        asm("v_permlane32_swap_b32 %0, %1" : "+v"(x1), "+v"(y1));
        asm("v_permlane16_swap_b32 %0, %1" : "+v"(x1), "+v"(y1));
        union { bf16x8 v; unsigned uu[4]; } B;
        B.uu[0] = x0; B.uu[1] = x1; B.uu[2] = y0; B.uu[3] = y1;
        __builtin_amdgcn_s_setprio(1);
#pragma unroll
        for (int dt = 0; dt < 4; ++dt) acc[u][dt] = MFMA16(vf[dt], B.v, acc[u][dt]);
        __builtin_amdgcn_s_setprio(0);
      }
    }
    // --- write next stage's tiles into the other buffer; lockstep barrier ---
    if (pre) swrite(buf ^ 1, kr, vr);
    __syncthreads();
  }

  // --- reduce l across h-groups (per q-column) ---
  float lt0 = l0 + __shfl_xor(l0, 16); lt0 += __shfl_xor(lt0, 32);
  float lt1 = l1 + __shfl_xor(l1, 16); lt1 += __shfl_xor(lt1, 32);

  // --- exact merge of kv-half j=1 into j=0 through dead K/V LDS ---
  float* fK = (float*)Kl;  // 4096 floats: slot(i,u,dt,h,r,qc)
  float* fV = (float*)Vl;  // (m,l) per (i,u,qc)
  if (j == 1) {
#pragma unroll
    for (int u = 0; u < 2; ++u) {
#pragma unroll
      for (int dt = 0; dt < 4; ++dt)
#pragma unroll
        for (int r = 0; r < 4; ++r)
          fK[((((i * 2 + u) * 4 + dt) * 4 + h) * 4 + r) * 16 + qc] = acc[u][dt][r];
      if (h == 0) {
        fV[((i * 2 + u) * 16 + qc) * 2] = (u == 0) ? m0 : m1;
        fV[((i * 2 + u) * 16 + qc) * 2 + 1] = (u == 0) ? lt0 : lt1;
      }
    }
  }
  __syncthreads();
  if (j == 0) {
#pragma unroll
    for (int u = 0; u < 2; ++u) {
      const float mA = (u == 0) ? m0 : m1;
      const float lA = (u == 0) ? lt0 : lt1;
      const float mB = fV[((i * 2 + u) * 16 + qc) * 2];
      const float lB = fV[((i * 2 + u) * 16 + qc) * 2 + 1];
      const float M = fmaxf(mA, mB);
      const float eA = exp2f(mA - M), eB = exp2f(mB - M);
      const float inv = 1.0f / (eA * lA + eB * lB);
      bf16* obp = ob + (size_t)(q0w + u * 16 + qc) * E + head * HD;
#pragma unroll
      for (int dt = 0; dt < 4; ++dt) {
        bf16x4 bb;
#pragma unroll
        for (int r = 0; r < 4; ++r) {
          float vB = fK[((((i * 2 + u) * 4 + dt) * 4 + h) * 4 + r) * 16 + qc];
          bb[r] = (bf16)((eA * acc[u][dt][r] + eB * vB) * inv);
        }
        *reinterpret_cast<bf16x4*>(obp + 16 * dt + 4 * h) = bb;
      }
    }
  }
}

// ---------------- output projection: out = attn @ wo^T, 128x128 tiles, B in LDS (R20-verified) ----------------
__global__ __launch_bounds__(256) void out_gemm_kernel(
    const bf16* __restrict__ ob, const bf16* __restrict__ wob,
    float* __restrict__ out) {
  __shared__ bf16 Bl[2][128 * 64];  // [buf][col*64 + swizzled kk]  (2 x 16 KB)
  const int tid = threadIdx.x;
  const int w = tid >> 6, l = tid & 63, lg = l >> 4, lr = l & 15;
  const int s0 = blockIdx.x * 128, e0 = blockIdx.y * 128;
  f32x4 acc[2][8];
#pragma unroll
  for (int rt = 0; rt < 2; ++rt)
#pragma unroll
    for (int ct = 0; ct < 8; ++ct) acc[rt][ct] = f32x4{0.f, 0.f, 0.f, 0.f};
  const bf16* ap0 = ob + (size_t)(s0 + w * 32 + lr) * E;
  const bf16* ap1 = ap0 + (size_t)16 * E;

  auto gloadB = [&](int k0, bf16x8 (&br)[4]) {
#pragma unroll
    for (int jj = 0; jj < 4; ++jj) {
      const int g = tid + jj * 256;
      const int col = g >> 3, ge = g & 7;
      br[jj] = *reinterpret_cast<const bf16x8*>(wob + (size_t)(e0 + col) * E + k0 + ge * 8);
    }
  };
  auto swriteB = [&](int buf, bf16x8 (&br)[4]) {
#pragma unroll
    for (int jj = 0; jj < 4; ++jj) {
      const int g = tid + jj * 256;
      const int col = g >> 3, ge = g & 7;
      *reinterpret_cast<bf16x8*>(&Bl[buf][col * 64 + ((ge * 8) ^ ((col & 7) << 3))]) = br[jj];
    }
  };

  bf16x8 br[4];
  gloadB(0, br);
  swriteB(0, br);
  __syncthreads();

  for (int it = 0; it < 16; ++it) {
    const int k0 = it * 64;
    const int buf = it & 1;
    const bool pre = (it + 1 < 16);
    if (pre) gloadB(k0 + 64, br);  // issue early; landed by swriteB at iter end

    bf16x8 af[2][2];
#pragma unroll
    for (int ks = 0; ks < 2; ++ks) {
      af[0][ks] = *reinterpret_cast<const bf16x8*>(ap0 + k0 + ks * 32 + lg * 8);
      af[1][ks] = *reinterpret_cast<const bf16x8*>(ap1 + k0 + ks * 32 + lg * 8);
    }
#pragma unroll
    for (int ks = 0; ks < 2; ++ks)
#pragma unroll
      for (int ct = 0; ct < 8; ++ct) {
        bf16x8 bfr = *reinterpret_cast<const bf16x8*>(
            &Bl[buf][(ct * 16 + lr) * 64 + ((ks * 32 + lg * 8) ^ ((lr & 7) << 3))]);
        acc[0][ct] = MFMA16(af[0][ks], bfr, acc[0][ct]);
        acc[1][ct] = MFMA16(af[1][ks], bfr, acc[1][ct]);
      }
    if (pre) swriteB(buf ^ 1, br);
    __syncthreads();
  }

#pragma unroll
  for (int rt = 0; rt < 2; ++rt)
#pragma unroll
    for (int ct = 0; ct < 8; ++ct)
#pragma unroll
      for (int r = 0; r < 4; ++r)
        out[(size_t)(s0 + w * 32 + rt * 16 + lg * 4 + r) * E + e0 + ct * 16 + lr] =
            acc[rt][ct][r];
}

extern "C" void kernel_launch(void* const* d_in, const int* in_sizes, int n_in,
                              void* d_out, int out_size, void* d_ws, size_t ws_size,
                              hipStream_t stream) {
  const float* x  = (const float*)d_in[0];
  const float* wq = (const float*)d_in[1];
  const float* wk = (const float*)d_in[2];
  const float* wv = (const float*)d_in[3];
  const float* wo = (const float*)d_in[4];
  float* out = (float*)d_out;

  bf16* qb  = (bf16*)d_ws;                 // [H][S][HD]
  bf16* kb  = qb + (size_t)H * S * HD;     // [H][S][HD]
  bf16* vt  = kb + (size_t)H * S * HD;     // [H][HD][S]  (V transposed)
  bf16* ob  = vt + (size_t)H * S * HD;     // [S][E]
  bf16* wob = ob + (size_t)S * E;          // [E][E]

  qkv_cvt_kernel<<<dim3(S / 64, H + 1), 256, 0, stream>>>(x, wq, wk, wv, wo, qb, kb, vt, wob);
  attn_kernel<<<dim3(1024), 256, 0, stream>>>(qb, kb, vt, ob);
  out_gemm_kernel<<<dim3(S / 128, E / 128), 256, 0, stream>>>(ob, wob, out);
}